// Round 14
// baseline (122.746 us; speedup 1.0000x reference)
//
#include <hip/hip_runtime.h>

#define N_NODES 100000
#define N_EDGES 1600000
#define D 64
#define NBKT 391                          // 256-node buckets: dst>>8
#define REG 5120                          // padded region stride (mean 4096 + 16 sigma)
#define A_EPB 4096                        // edges per scatter block
#define A_I4 (A_EPB / 4)                  // 1024 int4 per block
#define N_I4 (N_EDGES / 4)                // 400000
#define TB 20                             // max edges/thread in pass B (TB*256 = 5120 = REG)

// sage persistent-grid geometry
#define NPW 16
#define SBLK 512
#define SAGE_BLOCKS 768                   // 3 blocks/CU exactly (LDS 3x49.7KB = 149KB)
#define NWAVES (SAGE_BLOCKS * (SBLK / 64))   // 6144
#define NUNITS (N_NODES / NPW)               // 6250
#define EXTRA (NUNITS - NWAVES)              // 106 leftover units
#define SPREAD 57                            // 57*105 < 6144: spreads extras over ~106 CUs

typedef __attribute__((ext_vector_type(8))) short bf16x8;
typedef __attribute__((ext_vector_type(4))) float f32x4;

__device__ __forceinline__ unsigned short f2bf(float f) {
    union { float f; unsigned u; } v; v.f = f;
    unsigned r = v.u + 0x7FFFu + ((v.u >> 16) & 1u);
    return (unsigned short)(r >> 16);
}
__device__ __forceinline__ float bf2f_u(unsigned h) {   // low 16 bits -> float
    union { unsigned u; float f; } v; v.u = h << 16;
    return v.f;
}

// ---------------- kernel A: scatter into padded bucket regions + x->bf16 convert ----
#define CVT_BLKS 6250                     // 1.6M float4 / 256
__global__ __launch_bounds__(256) void scatter_cvt(const float* __restrict__ x,
                                                   unsigned short* __restrict__ xb,
                                                   const int* __restrict__ ei,
                                                   unsigned* __restrict__ fc,
                                                   unsigned* __restrict__ bpairs) {
    __shared__ unsigned hc[NBKT];
    __shared__ unsigned hb[NBKT];
    const int blk = blockIdx.x;
    const int tid = threadIdx.x;
    if (blk < NBKT) {
        for (int k = tid; k < NBKT; k += 256) hc[k] = 0;
        __syncthreads();

        const int g0 = blk * A_I4;
        const int4* sptr = (const int4*)ei;
        const int4* dptr = (const int4*)(ei + N_EDGES);

        unsigned pay[16];    // (src<<8) | (dst & 255)
        unsigned meta[16];   // (bucket<<13) | lrank ; 0xFFFFFFFF = invalid
        #pragma unroll
        for (int t = 0; t < 4; ++t) {
            const int g = g0 + tid + t * 256;
            if (g < N_I4) {
                int4 s4 = sptr[g];
                int4 d4 = dptr[g];
                const int dd[4] = { d4.x, d4.y, d4.z, d4.w };
                const int ss[4] = { s4.x, s4.y, s4.z, s4.w };
                #pragma unroll
                for (int c = 0; c < 4; ++c) {
                    const unsigned b = (unsigned)dd[c] >> 8;
                    const unsigned lr = atomicAdd(&hc[b], 1u);
                    meta[t * 4 + c] = (b << 13) | lr;
                    pay[t * 4 + c]  = ((unsigned)ss[c] << 8) | ((unsigned)dd[c] & 255u);
                }
            } else {
                #pragma unroll
                for (int c = 0; c < 4; ++c) meta[t * 4 + c] = 0xFFFFFFFFu;
            }
        }
        __syncthreads();
        for (int k = tid; k < NBKT; k += 256) {
            unsigned c = hc[k];
            if (c) hb[k] = atomicAdd(&fc[k], c);   // fixed bases: no pre-scan needed
        }
        __syncthreads();
        #pragma unroll
        for (int e = 0; e < 16; ++e) {
            if (meta[e] != 0xFFFFFFFFu) {
                const unsigned b   = meta[e] >> 13;
                const unsigned lr  = meta[e] & 0x1FFFu;
                const unsigned pos = hb[b] + lr;
                if (pos < REG) bpairs[(size_t)b * REG + pos] = pay[e];  // safety clamp
            }
        }
    } else {
        const int j = (blk - NBKT) * 256 + tid;  // float4 item
        if (j < CVT_BLKS * 256) {
            float4 v = ((const float4*)x)[j];
            ushort4 o;
            o.x = f2bf(v.x); o.y = f2bf(v.y); o.z = f2bf(v.z); o.w = f2bf(v.w);
            ((ushort4*)xb)[j] = o;
        }
    }
}

// ---------------- kernel B: per-bucket CSR build (in place) + packed offsets ----------------
// offsets[n] = (deg << 13) | rel_start   (rel within bucket region; abs = bucket*REG + rel)
__global__ __launch_bounds__(256) void bucket_csr(const unsigned* __restrict__ fc,
                                                  unsigned* __restrict__ bpairs,
                                                  int* __restrict__ offsets) {
    __shared__ unsigned ncnt[256];
    __shared__ unsigned s[256];
    const int b   = blockIdx.x;
    const int tid = threadIdx.x;
    const unsigned base = (unsigned)b * REG;
    unsigned cnt = fc[b];
    if (cnt > REG) cnt = REG;              // safety clamp

    ncnt[tid] = 0;
    __syncthreads();

    unsigned pk[TB];
    unsigned rk[TB];
    #pragma unroll
    for (int t = 0; t < TB; ++t) {
        const unsigned i = (unsigned)tid + t * 256u;
        if (i < cnt) {
            const unsigned p = bpairs[base + i];
            pk[t] = p;
            rk[t] = atomicAdd(&ncnt[p & 255u], 1u);
        } else {
            pk[t] = 0xFFFFFFFFu;
        }
    }
    __syncthreads();

    // 256-wide inclusive scan of ncnt
    const unsigned v = ncnt[tid];
    s[tid] = v;
    __syncthreads();
    for (int off = 1; off < 256; off <<= 1) {
        unsigned u = (tid >= off) ? s[tid - off] : 0;
        __syncthreads();
        s[tid] += u;
        __syncthreads();
    }
    const unsigned excl = s[tid] - v;
    ncnt[tid] = excl;                       // reuse as per-node local offset
    const int n0 = b * 256;
    if (n0 + tid < N_NODES) offsets[n0 + tid] = (int)((v << 13) | excl);
    __syncthreads();

    #pragma unroll
    for (int t = 0; t < TB; ++t) {
        if (pk[t] != 0xFFFFFFFFu) {
            const unsigned p  = pk[t];
            const unsigned dl = p & 255u;
            bpairs[base + ncnt[dl] + rk[t]] = p >> 8;   // src
        }
    }
}

// 8 clamp-masked edge-pairs: lanes<32 take edge jj, lanes>=32 take edge jj+1,
// each lane holds 2 cols as a packed bf16 pair.
#define STEP8(SI, J, N, A0, A1)                                              \
    {                                                                         \
        _Pragma("unroll")                                                     \
        for (int t_ = 0; t_ < 8; ++t_) {                                      \
            const int jj_  = (J) + 2 * t_;                                    \
            const int jlo_ = (jj_     < (N)) ? jj_     : ((N) - 1);           \
            const int jhi_ = (jj_ + 1 < (N)) ? jj_ + 1 : ((N) - 1);           \
            const int slo_ = __builtin_amdgcn_readlane((SI), jlo_);           \
            const int shi_ = __builtin_amdgcn_readlane((SI), jhi_);           \
            const int sel_ = (lane >= 32) ? shi_ : slo_;                      \
            unsigned v_ = xb32[(size_t)sel_ * 32 + lc];                       \
            const bool ok_ = (lane < 32) ? (jj_ < (N)) : (jj_ + 1 < (N));     \
            v_ = ok_ ? v_ : 0u;                                               \
            (A0) += bf2f_u(v_ & 0xFFFFu);                                     \
            (A1) += bf2f_u(v_ >> 16);                                         \
        }                                                                     \
    }

// rare tail for degree > 64
#define TAILCH(S0, DD, A0, A1)                                               \
    for (int base_ = 64; base_ < (DD); base_ += 64) {                        \
        const int n2_ = ((DD) - base_ < 64) ? ((DD) - base_) : 64;           \
        const int cl2_ = (lane < n2_) ? lane : (n2_ - 1);                    \
        const int sit_ = csr[(S0) + base_ + cl2_];                           \
        for (int j_ = 0; j_ < n2_; j_ += 16) { STEP8(sit_, j_, n2_, A0, A1) }\
    }

// ---------------- fused gather + mean + MFMA matmul + bias + ReLU ----------------
// Persistent grid: 768 blocks = 3/CU resident; wave w does unit w, plus the
// 106 leftover units mapped to waves w = 57k (k < 106) -> ~106 distinct CUs.
__global__ __launch_bounds__(SBLK) void sage_kernel(const unsigned short* __restrict__ xb,
                                                    const int* __restrict__ offsets,
                                                    const int* __restrict__ csr,
                                                    const float* __restrict__ Wl,
                                                    const float* __restrict__ bl,
                                                    const float* __restrict__ Wr,
                                                    float* __restrict__ out) {
    __shared__ unsigned short sWt[D * 2 * D];      // 64 cols x 128 k, 16 KB
    __shared__ float sbl[D];
    __shared__ unsigned int sA32[(SBLK / 64) * NPW * (2 * D / 2)];  // 8 waves x 16 rows x 64 uints

    const int tid = threadIdx.x;
    for (int i = tid; i < D * D; i += SBLK) {
        int k = i >> 6, c = i & 63;
        int swz = (c & 7) << 3;                     // ushort-index xor
        sWt[(c * 128 + k) ^ swz]      = f2bf(Wl[i]);
        sWt[(c * 128 + 64 + k) ^ swz] = f2bf(Wr[i]);
    }
    if (tid < D) sbl[tid] = bl[tid];
    __syncthreads();

    const int lane = tid & 63;
    const int wib  = tid >> 6;
    const int wwav = (blockIdx.x * (SBLK / 64)) + wib;   // 0..NWAVES-1

    const unsigned int* __restrict__ xb32 = (const unsigned int*)xb;
    unsigned int* sAw = sA32 + wib * (NPW * 64);
    const int lc = lane & 31;

    for (int pass = 0; pass < 2; ++pass) {
        int u;
        if (pass == 0) {
            u = wwav;
        } else {
            if (wwav % SPREAD != 0) break;
            const int k = wwav / SPREAD;
            if (k >= EXTRA) break;
            u = NWAVES + k;
        }
        const int node0 = u * NPW;
        const int bb = (node0 >> 8) * REG;          // bucket base (unit shares one bucket)

        // ---- stage packed offsets for 16 nodes with one lane-parallel load ----
        const int offl = offsets[node0 + (lane & 15)];

        // ---- stage csr chunk 0 for all 16 nodes (16 loads in flight) ----
        int si[NPW];
        int dg[NPW];
        #pragma unroll
        for (int r = 0; r < NPW; ++r) {
            const int er = __builtin_amdgcn_readlane(offl, r);
            const int d  = (int)((unsigned)er >> 13);
            dg[r] = d;
            const int s0 = bb + (er & 0x1FFF);
            const int dm = (d > 0) ? d : 1;
            const int cl = (lane < dm) ? lane : (dm - 1);
            si[r] = csr[s0 + cl];
        }

        // ---- gather: two nodes interleaved (16 xb loads in flight) ----
        #pragma unroll
        for (int p = 0; p < NPW / 2; ++p) {
            const int rA = 2 * p, rB = 2 * p + 1;
            const int dA = dg[rA], dB = dg[rB];
            const int nA = (dA < 64) ? dA : 64;
            const int nB = (dB < 64) ? dB : 64;

            const unsigned vselfA = xb32[(size_t)(node0 + rA) * 32 + lc];
            const unsigned vselfB = xb32[(size_t)(node0 + rB) * 32 + lc];

            float a0 = 0.0f, a1 = 0.0f, b0 = 0.0f, b1 = 0.0f;
            int jA = 0, jB = 0;
            while (jA < nA && jB < nB) {
                STEP8(si[rA], jA, nA, a0, a1)
                STEP8(si[rB], jB, nB, b0, b1)
                jA += 16; jB += 16;
            }
            while (jA < nA) { STEP8(si[rA], jA, nA, a0, a1) jA += 16; }
            while (jB < nB) { STEP8(si[rB], jB, nB, b0, b1) jB += 16; }
            if (dA > 64) {
                const int s0A = bb + (__builtin_amdgcn_readlane(offl, rA) & 0x1FFF);
                TAILCH(s0A, dA, a0, a1)
            }
            if (dB > 64) {
                const int s0B = bb + (__builtin_amdgcn_readlane(offl, rB) & 0x1FFF);
                TAILCH(s0B, dB, b0, b1)
            }

            a0 += __shfl_xor(a0, 32, 64);
            a1 += __shfl_xor(a1, 32, 64);
            b0 += __shfl_xor(b0, 32, 64);
            b1 += __shfl_xor(b1, 32, 64);
            const float invA = 1.0f / fmaxf((float)dA, 1.0f);
            const float invB = 1.0f / fmaxf((float)dB, 1.0f);
            const unsigned mpA = ((unsigned)f2bf(a1 * invA) << 16) | f2bf(a0 * invA);
            const unsigned mpB = ((unsigned)f2bf(b1 * invB) << 16) | f2bf(b0 * invB);
            const int swzA = (rA & 7) << 2;
            const int swzB = (rB & 7) << 2;
            if (lane < 32) {
                sAw[(rA * 64 + lc) ^ swzA] = mpA;
                sAw[(rB * 64 + lc) ^ swzB] = mpB;
            } else {
                sAw[(rA * 64 + 32 + lc) ^ swzA] = vselfA;
                sAw[(rB * 64 + 32 + lc) ^ swzB] = vselfB;
            }
        }

        // ---- MFMA phase ----
        const unsigned short* sAu = (const unsigned short*)sAw;
        const int row = lane & 15;
        const int kb  = lane >> 4;

        bf16x8 afr[4];
        #pragma unroll
        for (int kc = 0; kc < 4; ++kc) {
            int us = (row * 128 + kc * 32 + kb * 8) ^ ((row & 7) << 3);
            afr[kc] = *(const bf16x8*)(sAu + us);
        }

        #pragma unroll
        for (int ct = 0; ct < 4; ++ct) {
            const int col = ct * 16 + row;
            f32x4 acc = {0.0f, 0.0f, 0.0f, 0.0f};
            #pragma unroll
            for (int kc = 0; kc < 4; ++kc) {
                int us = (col * 128 + kc * 32 + kb * 8) ^ ((col & 7) << 3);
                bf16x8 bfr = *(const bf16x8*)(sWt + us);
                acc = __builtin_amdgcn_mfma_f32_16x16x32_bf16(afr[kc], bfr, acc, 0, 0, 0);
            }
            const float bias = sbl[col];
            const int crow0 = (lane >> 4) * 4;
            #pragma unroll
            for (int i = 0; i < 4; ++i) {
                out[(node0 + crow0 + i) * D + col] = fmaxf(acc[i] + bias, 0.0f);
            }
        }
    }
}

// ---------------- launch ----------------
extern "C" void kernel_launch(void* const* d_in, const int* in_sizes, int n_in,
                              void* d_out, int out_size, void* d_ws, size_t ws_size,
                              hipStream_t stream) {
    const float* x  = (const float*)d_in[0];
    const int*   ei = (const int*)d_in[1];    // [2, N_EDGES] flat: src then dst
    const float* Wl = (const float*)d_in[2];
    const float* bl = (const float*)d_in[3];
    const float* Wr = (const float*)d_in[4];
    float* out = (float*)d_out;

    // workspace layout (~21.2 MB), 16B-aligned segments
    unsigned* fc      = (unsigned*)d_ws;                 // 391 -> pad 512
    int* offsets      = (int*)(fc + 512);                // N_NODES -> pad 100004
    unsigned* bpairs  = (unsigned*)(offsets + 100004);   // NBKT*REG + 64 (csr in place)
    unsigned short* xb = (unsigned short*)(bpairs + (size_t)NBKT * REG + 64);  // N_NODES*D

    hipMemsetAsync(fc, 0, 512 * sizeof(unsigned), stream);

    scatter_cvt<<<NBKT + CVT_BLKS, 256, 0, stream>>>(x, xb, ei, fc, bpairs);
    bucket_csr<<<NBKT, 256, 0, stream>>>(fc, bpairs, offsets);

    sage_kernel<<<SAGE_BLOCKS, SBLK, 0, stream>>>(xb, offsets, (const int*)bpairs,
                                                  Wl, bl, Wr, out);
}

// Round 15
// 106.631 us; speedup vs baseline: 1.1511x; 1.1511x over previous
//
#include <hip/hip_runtime.h>

#define N_NODES 100000
#define N_EDGES 1600000
#define D 64
#define NBKT 391                          // 256-node buckets: dst>>8
#define REG 5120                          // padded region stride (mean 4096 + 16 sigma)
#define A_EPB 4096                        // edges per scatter block
#define A_I4 (A_EPB / 4)                  // 1024 int4 per block
#define N_I4 (N_EDGES / 4)                // 400000
#define TB 20                             // max edges/thread in pass B (TB*256 = 5120 = REG)

typedef __attribute__((ext_vector_type(8))) short bf16x8;
typedef __attribute__((ext_vector_type(4))) float f32x4;

__device__ __forceinline__ unsigned short f2bf(float f) {
    union { float f; unsigned u; } v; v.f = f;
    unsigned r = v.u + 0x7FFFu + ((v.u >> 16) & 1u);
    return (unsigned short)(r >> 16);
}

// ---------------- kernel A: scatter into padded bucket regions + x->fp8 convert ----
#define CVT_ITEMS ((N_NODES * D) / 4)     // 1.6M items: 4 floats -> 1 packed fp8 uint
#define CVT_BLKS 6250
__global__ __launch_bounds__(256) void scatter_cvt(const float* __restrict__ x,
                                                   unsigned* __restrict__ xq,
                                                   const int* __restrict__ ei,
                                                   unsigned* __restrict__ fc,
                                                   unsigned* __restrict__ bpairs) {
    __shared__ unsigned hc[NBKT];
    __shared__ unsigned hb[NBKT];
    const int blk = blockIdx.x;
    const int tid = threadIdx.x;
    if (blk < NBKT) {
        for (int k = tid; k < NBKT; k += 256) hc[k] = 0;
        __syncthreads();

        const int g0 = blk * A_I4;
        const int4* sptr = (const int4*)ei;
        const int4* dptr = (const int4*)(ei + N_EDGES);

        unsigned pay[16];    // (src<<8) | (dst & 255)
        unsigned meta[16];   // (bucket<<13) | lrank ; 0xFFFFFFFF = invalid
        #pragma unroll
        for (int t = 0; t < 4; ++t) {
            const int g = g0 + tid + t * 256;
            if (g < N_I4) {
                int4 s4 = sptr[g];
                int4 d4 = dptr[g];
                const int dd[4] = { d4.x, d4.y, d4.z, d4.w };
                const int ss[4] = { s4.x, s4.y, s4.z, s4.w };
                #pragma unroll
                for (int c = 0; c < 4; ++c) {
                    const unsigned b = (unsigned)dd[c] >> 8;
                    const unsigned lr = atomicAdd(&hc[b], 1u);
                    meta[t * 4 + c] = (b << 13) | lr;
                    pay[t * 4 + c]  = ((unsigned)ss[c] << 8) | ((unsigned)dd[c] & 255u);
                }
            } else {
                #pragma unroll
                for (int c = 0; c < 4; ++c) meta[t * 4 + c] = 0xFFFFFFFFu;
            }
        }
        __syncthreads();
        for (int k = tid; k < NBKT; k += 256) {
            unsigned c = hc[k];
            if (c) hb[k] = atomicAdd(&fc[k], c);   // fixed bases: no pre-scan needed
        }
        __syncthreads();
        #pragma unroll
        for (int e = 0; e < 16; ++e) {
            if (meta[e] != 0xFFFFFFFFu) {
                const unsigned b   = meta[e] >> 13;
                const unsigned lr  = meta[e] & 0x1FFFu;
                const unsigned pos = hb[b] + lr;
                if (pos < REG) bpairs[(size_t)b * REG + pos] = pay[e];  // safety clamp
            }
        }
    } else {
        const int j = (blk - NBKT) * 256 + tid;  // packed-fp8 item
        if (j < CVT_ITEMS) {
            float4 v = ((const float4*)x)[j];
            unsigned u = __builtin_amdgcn_cvt_pk_fp8_f32(v.x, v.y, 0u, false);
            u = __builtin_amdgcn_cvt_pk_fp8_f32(v.z, v.w, u, true);
            xq[j] = u;
        }
    }
}

// ---------------- kernel B: per-bucket CSR build (in place) + packed offsets ----------------
// offsets[n] = (deg << 13) | rel_start   (rel within bucket region; abs = bucket*REG + rel)
__global__ __launch_bounds__(256) void bucket_csr(const unsigned* __restrict__ fc,
                                                  unsigned* __restrict__ bpairs,
                                                  int* __restrict__ offsets) {
    __shared__ unsigned ncnt[256];
    __shared__ unsigned s[256];
    const int b   = blockIdx.x;
    const int tid = threadIdx.x;
    const unsigned base = (unsigned)b * REG;
    unsigned cnt = fc[b];
    if (cnt > REG) cnt = REG;              // safety clamp

    ncnt[tid] = 0;
    __syncthreads();

    unsigned pk[TB];
    unsigned rk[TB];
    #pragma unroll
    for (int t = 0; t < TB; ++t) {
        const unsigned i = (unsigned)tid + t * 256u;
        if (i < cnt) {
            const unsigned p = bpairs[base + i];
            pk[t] = p;
            rk[t] = atomicAdd(&ncnt[p & 255u], 1u);
        } else {
            pk[t] = 0xFFFFFFFFu;
        }
    }
    __syncthreads();

    // 256-wide inclusive scan of ncnt
    const unsigned v = ncnt[tid];
    s[tid] = v;
    __syncthreads();
    for (int off = 1; off < 256; off <<= 1) {
        unsigned u = (tid >= off) ? s[tid - off] : 0;
        __syncthreads();
        s[tid] += u;
        __syncthreads();
    }
    const unsigned excl = s[tid] - v;
    ncnt[tid] = excl;                       // reuse as per-node local offset
    const int n0 = b * 256;
    if (n0 + tid < N_NODES) offsets[n0 + tid] = (int)((v << 13) | excl);
    __syncthreads();

    #pragma unroll
    for (int t = 0; t < TB; ++t) {
        if (pk[t] != 0xFFFFFFFFu) {
            const unsigned p  = pk[t];
            const unsigned dl = p & 255u;
            bpairs[base + ncnt[dl] + rk[t]] = p >> 8;   // src
        }
    }
}

// fp8 gather step: 4 sub-iters x 4 edges. Lane group g = lane>>4 takes edge e+g;
// each lane holds 4 fp8 cols (4*(lane&15)..+3) of that edge's row (1 line/row).
#define STEPF(SI, J, N, A0, A1, A2, A3)                                      \
    {                                                                         \
        _Pragma("unroll")                                                     \
        for (int t_ = 0; t_ < 4; ++t_) {                                      \
            const int e_  = (J) + 4 * t_;                                     \
            const int c0_ = (e_     < (N)) ? e_     : ((N) - 1);              \
            const int c1_ = (e_ + 1 < (N)) ? e_ + 1 : ((N) - 1);              \
            const int c2_ = (e_ + 2 < (N)) ? e_ + 2 : ((N) - 1);              \
            const int c3_ = (e_ + 3 < (N)) ? e_ + 3 : ((N) - 1);              \
            const int i0_ = __builtin_amdgcn_readlane((SI), c0_);             \
            const int i1_ = __builtin_amdgcn_readlane((SI), c1_);             \
            const int i2_ = __builtin_amdgcn_readlane((SI), c2_);             \
            const int i3_ = __builtin_amdgcn_readlane((SI), c3_);             \
            const int s01_ = g1 ? i1_ : i0_;                                  \
            const int s23_ = g1 ? i3_ : i2_;                                  \
            const int sel_ = g2 ? s23_ : s01_;                                \
            unsigned v_ = xq32[(size_t)sel_ * 16 + lq];                       \
            v_ = (e_ + grp < (N)) ? v_ : 0u;                                  \
            (A0) += __builtin_amdgcn_cvt_f32_fp8(v_, 0);                      \
            (A1) += __builtin_amdgcn_cvt_f32_fp8(v_, 1);                      \
            (A2) += __builtin_amdgcn_cvt_f32_fp8(v_, 2);                      \
            (A3) += __builtin_amdgcn_cvt_f32_fp8(v_, 3);                      \
        }                                                                     \
    }

// rare tail for degree > 64
#define TAILF(S0, DD, A0, A1, A2, A3)                                        \
    for (int b2_ = 64; b2_ < (DD); b2_ += 64) {                              \
        const int n2_ = ((DD) - b2_ < 64) ? ((DD) - b2_) : 64;               \
        const int cl2_ = (lane < n2_) ? lane : (n2_ - 1);                    \
        const int sit_ = csr[(S0) + b2_ + cl2_];                             \
        for (int j_ = 0; j_ < n2_; j_ += 16) {                               \
            STEPF(sit_, j_, n2_, A0, A1, A2, A3)                             \
        }                                                                     \
    }

// finish one node: cross-group butterfly, mean, bf16-pack, LDS store (lanes 0-15)
#define FINR(R, DV, A0, A1, A2, A3)                                          \
    {                                                                         \
        (A0) += __shfl_xor((A0), 16, 64); (A0) += __shfl_xor((A0), 32, 64);   \
        (A1) += __shfl_xor((A1), 16, 64); (A1) += __shfl_xor((A1), 32, 64);   \
        (A2) += __shfl_xor((A2), 16, 64); (A2) += __shfl_xor((A2), 32, 64);   \
        (A3) += __shfl_xor((A3), 16, 64); (A3) += __shfl_xor((A3), 32, 64);   \
        const float inv_ = 1.0f / fmaxf((float)(DV), 1.0f);                   \
        if (lane < 16) {                                                      \
            const unsigned m0_ = ((unsigned)f2bf((A1) * inv_) << 16)          \
                                 | f2bf((A0) * inv_);                         \
            const unsigned m1_ = ((unsigned)f2bf((A3) * inv_) << 16)          \
                                 | f2bf((A2) * inv_);                         \
            const int sw_ = ((R) & 7) << 2;                                   \
            sAw[((R) * 64 + 2 * lane) ^ sw_]     = m0_;                       \
            sAw[((R) * 64 + 2 * lane + 1) ^ sw_] = m1_;                       \
        }                                                                     \
    }

// ---------------- fused gather(fp8) + mean + MFMA matmul + bias + ReLU ----------------
#define NPW 16
#define SBLK 512
__global__ __launch_bounds__(SBLK) void sage_kernel(const float* __restrict__ x,
                                                    const unsigned* __restrict__ xq32,
                                                    const int* __restrict__ offsets,
                                                    const int* __restrict__ csr,
                                                    const float* __restrict__ Wl,
                                                    const float* __restrict__ bl,
                                                    const float* __restrict__ Wr,
                                                    float* __restrict__ out) {
    __shared__ unsigned short sWt[D * 2 * D];      // 64 cols x 128 k, 16 KB
    __shared__ float sbl[D];
    __shared__ unsigned int sA32[(SBLK / 64) * NPW * (2 * D / 2)];  // 8 waves x 16 rows x 64 uints

    const int tid = threadIdx.x;
    for (int i = tid; i < D * D; i += SBLK) {
        int k = i >> 6, c = i & 63;
        int swz = (c & 7) << 3;                     // ushort-index xor
        sWt[(c * 128 + k) ^ swz]      = f2bf(Wl[i]);
        sWt[(c * 128 + 64 + k) ^ swz] = f2bf(Wr[i]);
    }
    if (tid < D) sbl[tid] = bl[tid];
    __syncthreads();

    const int lane = tid & 63;
    const int wib  = tid >> 6;
    const int wid  = (blockIdx.x * (SBLK / 64)) + wib;
    const int node0 = wid * NPW;
    if (node0 >= N_NODES) return;

    unsigned int* sAw = sA32 + wib * (NPW * 64);
    const int grp = lane >> 4;                      // 0..3 edge-group
    const int lq  = lane & 15;                      // col-quad within row
    const bool g1 = (grp & 1) != 0;
    const bool g2 = (grp & 2) != 0;
    const int bb = (node0 >> 8) * REG;              // bucket base (wave's nodes share it)

    // ---- stage self rows from f32 x (contiguous; 8 insts, 2 rows each) ----
    {
        const float2* __restrict__ x2 = (const float2*)x;
        const int c = lane & 31;
        #pragma unroll
        for (int rr = 0; rr < 8; ++rr) {
            const int r = 2 * rr + (lane >> 5);
            float2 v = x2[(size_t)(node0 + r) * 32 + c];
            const unsigned mp = ((unsigned)f2bf(v.y) << 16) | f2bf(v.x);
            sAw[(r * 64 + 32 + c) ^ ((r & 7) << 2)] = mp;
        }
    }

    // ---- stage packed offsets for 16 nodes with one lane-parallel load ----
    const int offl = offsets[node0 + (lane & 15)];

    // ---- stage csr chunk 0 for all 16 nodes (16 loads in flight) ----
    int si[NPW];
    int dg[NPW];
    #pragma unroll
    for (int r = 0; r < NPW; ++r) {
        const int er = __builtin_amdgcn_readlane(offl, r);
        const int d  = (int)((unsigned)er >> 13);
        dg[r] = d;
        const int s0 = bb + (er & 0x1FFF);
        const int dm = (d > 0) ? d : 1;
        const int cl = (lane < dm) ? lane : (dm - 1);
        si[r] = csr[s0 + cl];
    }

    // ---- gather: two nodes interleaved, fp8 rows (1 line/edge) ----
    #pragma unroll
    for (int p = 0; p < NPW / 2; ++p) {
        const int rA = 2 * p, rB = 2 * p + 1;
        const int dA = dg[rA], dB = dg[rB];
        const int nA = (dA < 64) ? dA : 64;
        const int nB = (dB < 64) ? dB : 64;

        float a0 = 0.0f, a1 = 0.0f, a2 = 0.0f, a3 = 0.0f;
        float b0 = 0.0f, b1 = 0.0f, b2 = 0.0f, b3 = 0.0f;
        int jA = 0, jB = 0;
        while (jA < nA && jB < nB) {
            STEPF(si[rA], jA, nA, a0, a1, a2, a3)
            STEPF(si[rB], jB, nB, b0, b1, b2, b3)
            jA += 16; jB += 16;
        }
        while (jA < nA) { STEPF(si[rA], jA, nA, a0, a1, a2, a3) jA += 16; }
        while (jB < nB) { STEPF(si[rB], jB, nB, b0, b1, b2, b3) jB += 16; }
        if (dA > 64) {
            const int s0A = bb + (__builtin_amdgcn_readlane(offl, rA) & 0x1FFF);
            TAILF(s0A, dA, a0, a1, a2, a3)
        }
        if (dB > 64) {
            const int s0B = bb + (__builtin_amdgcn_readlane(offl, rB) & 0x1FFF);
            TAILF(s0B, dB, b0, b1, b2, b3)
        }

        FINR(rA, dA, a0, a1, a2, a3)
        FINR(rB, dB, b0, b1, b2, b3)
    }

    // ---- MFMA phase ----
    const unsigned short* sAu = (const unsigned short*)sAw;
    const int row = lane & 15;
    const int kb  = lane >> 4;

    bf16x8 afr[4];
    #pragma unroll
    for (int kc = 0; kc < 4; ++kc) {
        int us = (row * 128 + kc * 32 + kb * 8) ^ ((row & 7) << 3);
        afr[kc] = *(const bf16x8*)(sAu + us);
    }

    #pragma unroll
    for (int ct = 0; ct < 4; ++ct) {
        const int col = ct * 16 + row;
        f32x4 acc = {0.0f, 0.0f, 0.0f, 0.0f};
        #pragma unroll
        for (int kc = 0; kc < 4; ++kc) {
            int us = (col * 128 + kc * 32 + kb * 8) ^ ((col & 7) << 3);
            bf16x8 bfr = *(const bf16x8*)(sWt + us);
            acc = __builtin_amdgcn_mfma_f32_16x16x32_bf16(afr[kc], bfr, acc, 0, 0, 0);
        }
        const float bias = sbl[col];
        const int crow0 = (lane >> 4) * 4;
        #pragma unroll
        for (int i = 0; i < 4; ++i) {
            out[(node0 + crow0 + i) * D + col] = fmaxf(acc[i] + bias, 0.0f);
        }
    }
}

// ---------------- launch ----------------
extern "C" void kernel_launch(void* const* d_in, const int* in_sizes, int n_in,
                              void* d_out, int out_size, void* d_ws, size_t ws_size,
                              hipStream_t stream) {
    const float* x  = (const float*)d_in[0];
    const int*   ei = (const int*)d_in[1];    // [2, N_EDGES] flat: src then dst
    const float* Wl = (const float*)d_in[2];
    const float* bl = (const float*)d_in[3];
    const float* Wr = (const float*)d_in[4];
    float* out = (float*)d_out;

    // workspace layout (~14.8 MB), 16B-aligned segments
    unsigned* xq      = (unsigned*)d_ws;                 // 1.6M uints fp8 x (6.4 MB)
    unsigned* fc      = xq + (size_t)N_NODES * 16;       // 391 -> pad 512
    int* offsets      = (int*)(fc + 512);                // N_NODES -> pad 100004
    unsigned* bpairs  = (unsigned*)(offsets + 100004);   // NBKT*REG + 64 (csr in place)

    hipMemsetAsync(fc, 0, 512 * sizeof(unsigned), stream);

    scatter_cvt<<<NBKT + CVT_BLKS, 256, 0, stream>>>(x, xq, ei, fc, bpairs);
    bucket_csr<<<NBKT, 256, 0, stream>>>(fc, bpairs, offsets);

    {
        const int waves  = (N_NODES + NPW - 1) / NPW;               // 6250
        const int blocks = (waves + (SBLK / 64) - 1) / (SBLK / 64); // 782
        sage_kernel<<<blocks, SBLK, 0, stream>>>(x, xq, offsets, (const int*)bpairs,
                                                 Wl, bl, Wr, out);
    }
}

// Round 16
// 100.638 us; speedup vs baseline: 1.2197x; 1.0596x over previous
//
#include <hip/hip_runtime.h>

#define N_NODES 100000
#define N_EDGES 1600000
#define D 64
#define NBKT 391                          // 256-node buckets: dst>>8
#define REG 5120                          // padded region stride (mean 4096 + 16 sigma)
#define A_EPB 4096                        // edges per scatter block
#define SCB 1024                          // scatter/csr block threads
#define A_I4 (A_EPB / 4)                  // 1024 int4 per block (1 per thread)
#define N_I4 (N_EDGES / 4)                // 400000
#define TB 5                              // edges/thread in pass B (TB*1024 = 5120 = REG)

typedef __attribute__((ext_vector_type(8))) short bf16x8;
typedef __attribute__((ext_vector_type(4))) float f32x4;

__device__ __forceinline__ unsigned short f2bf(float f) {
    union { float f; unsigned u; } v; v.f = f;
    unsigned r = v.u + 0x7FFFu + ((v.u >> 16) & 1u);
    return (unsigned short)(r >> 16);
}

// ---------------- kernel A: scatter into padded bucket regions + x->fp8 convert ----
#define CVT_ITEMS ((N_NODES * D) / 4)     // 1.6M items: 4 floats -> 1 packed fp8 uint
#define CVT_BLKS 1563                     // 1563 * 1024 = 1600512 >= 1.6M
__global__ __launch_bounds__(SCB) void scatter_cvt(const float* __restrict__ x,
                                                   unsigned* __restrict__ xq,
                                                   const int* __restrict__ ei,
                                                   unsigned* __restrict__ fc,
                                                   unsigned* __restrict__ bpairs) {
    __shared__ unsigned hc[NBKT];
    __shared__ unsigned hb[NBKT];
    const int blk = blockIdx.x;
    const int tid = threadIdx.x;
    if (blk < NBKT) {
        if (tid < NBKT) hc[tid] = 0;
        __syncthreads();

        const int g = blk * A_I4 + tid;            // one int4 (4 edges) per thread
        const int4* sptr = (const int4*)ei;
        const int4* dptr = (const int4*)(ei + N_EDGES);

        unsigned pay[4];     // (src<<8) | (dst & 255)
        unsigned meta[4];    // (bucket<<13) | lrank ; 0xFFFFFFFF = invalid
        if (g < N_I4) {
            int4 s4 = sptr[g];
            int4 d4 = dptr[g];
            const int dd[4] = { d4.x, d4.y, d4.z, d4.w };
            const int ss[4] = { s4.x, s4.y, s4.z, s4.w };
            #pragma unroll
            for (int c = 0; c < 4; ++c) {
                const unsigned b = (unsigned)dd[c] >> 8;
                const unsigned lr = atomicAdd(&hc[b], 1u);
                meta[c] = (b << 13) | lr;
                pay[c]  = ((unsigned)ss[c] << 8) | ((unsigned)dd[c] & 255u);
            }
        } else {
            #pragma unroll
            for (int c = 0; c < 4; ++c) meta[c] = 0xFFFFFFFFu;
        }
        __syncthreads();
        if (tid < NBKT) {
            unsigned c = hc[tid];
            if (c) hb[tid] = atomicAdd(&fc[tid], c);   // fixed bases: no pre-scan
        }
        __syncthreads();
        #pragma unroll
        for (int e = 0; e < 4; ++e) {
            if (meta[e] != 0xFFFFFFFFu) {
                const unsigned b   = meta[e] >> 13;
                const unsigned lr  = meta[e] & 0x1FFFu;
                const unsigned pos = hb[b] + lr;
                if (pos < REG) bpairs[(size_t)b * REG + pos] = pay[e];  // safety clamp
            }
        }
    } else {
        const int j = (blk - NBKT) * SCB + tid;    // packed-fp8 item
        if (j < CVT_ITEMS) {
            float4 v = ((const float4*)x)[j];
            unsigned u = __builtin_amdgcn_cvt_pk_fp8_f32(v.x, v.y, 0u, false);
            u = __builtin_amdgcn_cvt_pk_fp8_f32(v.z, v.w, u, true);
            xq[j] = u;
        }
    }
}

// ---------------- kernel B: per-bucket CSR build (in place) + packed offsets ----------------
// offsets[n] = (deg << 13) | rel_start   (rel within bucket region; abs = bucket*REG + rel)
__global__ __launch_bounds__(SCB) void bucket_csr(const unsigned* __restrict__ fc,
                                                  unsigned* __restrict__ bpairs,
                                                  int* __restrict__ offsets) {
    __shared__ unsigned ncnt[256];
    __shared__ unsigned s[256];
    const int b   = blockIdx.x;
    const int tid = threadIdx.x;
    const unsigned base = (unsigned)b * REG;
    unsigned cnt = fc[b];
    if (cnt > REG) cnt = REG;              // safety clamp

    if (tid < 256) ncnt[tid] = 0;
    __syncthreads();

    unsigned pk[TB];
    unsigned rk[TB];
    #pragma unroll
    for (int t = 0; t < TB; ++t) {
        const unsigned i = (unsigned)tid + t * (unsigned)SCB;
        if (i < cnt) {
            const unsigned p = bpairs[base + i];
            pk[t] = p;
            rk[t] = atomicAdd(&ncnt[p & 255u], 1u);
        } else {
            pk[t] = 0xFFFFFFFFu;
        }
    }
    __syncthreads();

    // 256-wide inclusive scan of ncnt on tids 0-255 (block-wide barriers)
    unsigned v = 0;
    if (tid < 256) { v = ncnt[tid]; s[tid] = v; }
    __syncthreads();
    for (int off = 1; off < 256; off <<= 1) {
        unsigned u = 0;
        if (tid < 256 && tid >= off) u = s[tid - off];
        __syncthreads();
        if (tid < 256) s[tid] += u;
        __syncthreads();
    }
    if (tid < 256) {
        const unsigned excl = s[tid] - v;
        ncnt[tid] = excl;                   // reuse as per-node local offset
        const int n0 = b * 256;
        if (n0 + tid < N_NODES) offsets[n0 + tid] = (int)((v << 13) | excl);
    }
    __syncthreads();

    #pragma unroll
    for (int t = 0; t < TB; ++t) {
        if (pk[t] != 0xFFFFFFFFu) {
            const unsigned p  = pk[t];
            const unsigned dl = p & 255u;
            bpairs[base + ncnt[dl] + rk[t]] = p >> 8;   // src
        }
    }
}

// fp8 gather step: 4 sub-iters x 4 edges. Lane group g = lane>>4 takes edge e+g;
// each lane holds 4 fp8 cols (4*(lane&15)..+3) of that edge's row (1 line/row).
#define STEPF(SI, J, N, A0, A1, A2, A3)                                      \
    {                                                                         \
        _Pragma("unroll")                                                     \
        for (int t_ = 0; t_ < 4; ++t_) {                                      \
            const int e_  = (J) + 4 * t_;                                     \
            const int c0_ = (e_     < (N)) ? e_     : ((N) - 1);              \
            const int c1_ = (e_ + 1 < (N)) ? e_ + 1 : ((N) - 1);              \
            const int c2_ = (e_ + 2 < (N)) ? e_ + 2 : ((N) - 1);              \
            const int c3_ = (e_ + 3 < (N)) ? e_ + 3 : ((N) - 1);              \
            const int i0_ = __builtin_amdgcn_readlane((SI), c0_);             \
            const int i1_ = __builtin_amdgcn_readlane((SI), c1_);             \
            const int i2_ = __builtin_amdgcn_readlane((SI), c2_);             \
            const int i3_ = __builtin_amdgcn_readlane((SI), c3_);             \
            const int s01_ = g1 ? i1_ : i0_;                                  \
            const int s23_ = g1 ? i3_ : i2_;                                  \
            const int sel_ = g2 ? s23_ : s01_;                                \
            unsigned v_ = xq32[(size_t)sel_ * 16 + lq];                       \
            v_ = (e_ + grp < (N)) ? v_ : 0u;                                  \
            (A0) += __builtin_amdgcn_cvt_f32_fp8(v_, 0);                      \
            (A1) += __builtin_amdgcn_cvt_f32_fp8(v_, 1);                      \
            (A2) += __builtin_amdgcn_cvt_f32_fp8(v_, 2);                      \
            (A3) += __builtin_amdgcn_cvt_f32_fp8(v_, 3);                      \
        }                                                                     \
    }

// rare tail for degree > 64
#define TAILF(S0, DD, A0, A1, A2, A3)                                        \
    for (int b2_ = 64; b2_ < (DD); b2_ += 64) {                              \
        const int n2_ = ((DD) - b2_ < 64) ? ((DD) - b2_) : 64;               \
        const int cl2_ = (lane < n2_) ? lane : (n2_ - 1);                    \
        const int sit_ = csr[(S0) + b2_ + cl2_];                             \
        for (int j_ = 0; j_ < n2_; j_ += 16) {                               \
            STEPF(sit_, j_, n2_, A0, A1, A2, A3)                             \
        }                                                                     \
    }

// finish one node: cross-group butterfly, mean, bf16-pack, LDS store (lanes 0-15)
#define FINR(R, DV, A0, A1, A2, A3)                                          \
    {                                                                         \
        (A0) += __shfl_xor((A0), 16, 64); (A0) += __shfl_xor((A0), 32, 64);   \
        (A1) += __shfl_xor((A1), 16, 64); (A1) += __shfl_xor((A1), 32, 64);   \
        (A2) += __shfl_xor((A2), 16, 64); (A2) += __shfl_xor((A2), 32, 64);   \
        (A3) += __shfl_xor((A3), 16, 64); (A3) += __shfl_xor((A3), 32, 64);   \
        const float inv_ = 1.0f / fmaxf((float)(DV), 1.0f);                   \
        if (lane < 16) {                                                      \
            const unsigned m0_ = ((unsigned)f2bf((A1) * inv_) << 16)          \
                                 | f2bf((A0) * inv_);                         \
            const unsigned m1_ = ((unsigned)f2bf((A3) * inv_) << 16)          \
                                 | f2bf((A2) * inv_);                         \
            const int sw_ = ((R) & 7) << 2;                                   \
            sAw[((R) * 64 + 2 * lane) ^ sw_]     = m0_;                       \
            sAw[((R) * 64 + 2 * lane + 1) ^ sw_] = m1_;                       \
        }                                                                     \
    }

// ---------------- fused gather(fp8) + mean + MFMA matmul + bias + ReLU ----------------
#define NPW 16
#define SBLK 512
__global__ __launch_bounds__(SBLK) void sage_kernel(const float* __restrict__ x,
                                                    const unsigned* __restrict__ xq32,
                                                    const int* __restrict__ offsets,
                                                    const int* __restrict__ csr,
                                                    const float* __restrict__ Wl,
                                                    const float* __restrict__ bl,
                                                    const float* __restrict__ Wr,
                                                    float* __restrict__ out) {
    __shared__ unsigned short sWt[D * 2 * D];      // 64 cols x 128 k, 16 KB
    __shared__ float sbl[D];
    __shared__ unsigned int sA32[(SBLK / 64) * NPW * (2 * D / 2)];  // 8 waves x 16 rows x 64 uints

    const int tid = threadIdx.x;
    for (int i = tid; i < D * D; i += SBLK) {
        int k = i >> 6, c = i & 63;
        int swz = (c & 7) << 3;                     // ushort-index xor
        sWt[(c * 128 + k) ^ swz]      = f2bf(Wl[i]);
        sWt[(c * 128 + 64 + k) ^ swz] = f2bf(Wr[i]);
    }
    if (tid < D) sbl[tid] = bl[tid];
    __syncthreads();

    const int lane = tid & 63;
    const int wib  = tid >> 6;
    const int wid  = (blockIdx.x * (SBLK / 64)) + wib;
    const int node0 = wid * NPW;
    if (node0 >= N_NODES) return;

    unsigned int* sAw = sA32 + wib * (NPW * 64);
    const int grp = lane >> 4;                      // 0..3 edge-group
    const int lq  = lane & 15;                      // col-quad within row
    const bool g1 = (grp & 1) != 0;
    const bool g2 = (grp & 2) != 0;
    const int bb = (node0 >> 8) * REG;              // bucket base (wave's nodes share it)

    // ---- stage self rows from f32 x (contiguous; 8 insts, 2 rows each) ----
    {
        const float2* __restrict__ x2 = (const float2*)x;
        const int c = lane & 31;
        #pragma unroll
        for (int rr = 0; rr < 8; ++rr) {
            const int r = 2 * rr + (lane >> 5);
            float2 v = x2[(size_t)(node0 + r) * 32 + c];
            const unsigned mp = ((unsigned)f2bf(v.y) << 16) | f2bf(v.x);
            sAw[(r * 64 + 32 + c) ^ ((r & 7) << 2)] = mp;
        }
    }

    // ---- stage packed offsets for 16 nodes with one lane-parallel load ----
    const int offl = offsets[node0 + (lane & 15)];

    // ---- stage csr chunk 0 for all 16 nodes (16 loads in flight) ----
    int si[NPW];
    int dg[NPW];
    #pragma unroll
    for (int r = 0; r < NPW; ++r) {
        const int er = __builtin_amdgcn_readlane(offl, r);
        const int d  = (int)((unsigned)er >> 13);
        dg[r] = d;
        const int s0 = bb + (er & 0x1FFF);
        const int dm = (d > 0) ? d : 1;
        const int cl = (lane < dm) ? lane : (dm - 1);
        si[r] = csr[s0 + cl];
    }

    // ---- gather: two nodes interleaved, fp8 rows (1 line/edge) ----
    #pragma unroll
    for (int p = 0; p < NPW / 2; ++p) {
        const int rA = 2 * p, rB = 2 * p + 1;
        const int dA = dg[rA], dB = dg[rB];
        const int nA = (dA < 64) ? dA : 64;
        const int nB = (dB < 64) ? dB : 64;

        float a0 = 0.0f, a1 = 0.0f, a2 = 0.0f, a3 = 0.0f;
        float b0 = 0.0f, b1 = 0.0f, b2 = 0.0f, b3 = 0.0f;
        int jA = 0, jB = 0;
        while (jA < nA && jB < nB) {
            STEPF(si[rA], jA, nA, a0, a1, a2, a3)
            STEPF(si[rB], jB, nB, b0, b1, b2, b3)
            jA += 16; jB += 16;
        }
        while (jA < nA) { STEPF(si[rA], jA, nA, a0, a1, a2, a3) jA += 16; }
        while (jB < nB) { STEPF(si[rB], jB, nB, b0, b1, b2, b3) jB += 16; }
        if (dA > 64) {
            const int s0A = bb + (__builtin_amdgcn_readlane(offl, rA) & 0x1FFF);
            TAILF(s0A, dA, a0, a1, a2, a3)
        }
        if (dB > 64) {
            const int s0B = bb + (__builtin_amdgcn_readlane(offl, rB) & 0x1FFF);
            TAILF(s0B, dB, b0, b1, b2, b3)
        }

        FINR(rA, dA, a0, a1, a2, a3)
        FINR(rB, dB, b0, b1, b2, b3)
    }

    // ---- MFMA phase ----
    const unsigned short* sAu = (const unsigned short*)sAw;
    const int row = lane & 15;
    const int kb  = lane >> 4;

    bf16x8 afr[4];
    #pragma unroll
    for (int kc = 0; kc < 4; ++kc) {
        int us = (row * 128 + kc * 32 + kb * 8) ^ ((row & 7) << 3);
        afr[kc] = *(const bf16x8*)(sAu + us);
    }

    #pragma unroll
    for (int ct = 0; ct < 4; ++ct) {
        const int col = ct * 16 + row;
        f32x4 acc = {0.0f, 0.0f, 0.0f, 0.0f};
        #pragma unroll
        for (int kc = 0; kc < 4; ++kc) {
            int us = (col * 128 + kc * 32 + kb * 8) ^ ((col & 7) << 3);
            bf16x8 bfr = *(const bf16x8*)(sWt + us);
            acc = __builtin_amdgcn_mfma_f32_16x16x32_bf16(afr[kc], bfr, acc, 0, 0, 0);
        }
        const float bias = sbl[col];
        const int crow0 = (lane >> 4) * 4;
        #pragma unroll
        for (int i = 0; i < 4; ++i) {
            out[(node0 + crow0 + i) * D + col] = fmaxf(acc[i] + bias, 0.0f);
        }
    }
}

// ---------------- launch ----------------
extern "C" void kernel_launch(void* const* d_in, const int* in_sizes, int n_in,
                              void* d_out, int out_size, void* d_ws, size_t ws_size,
                              hipStream_t stream) {
    const float* x  = (const float*)d_in[0];
    const int*   ei = (const int*)d_in[1];    // [2, N_EDGES] flat: src then dst
    const float* Wl = (const float*)d_in[2];
    const float* bl = (const float*)d_in[3];
    const float* Wr = (const float*)d_in[4];
    float* out = (float*)d_out;

    // workspace layout (~14.8 MB), 16B-aligned segments
    unsigned* xq      = (unsigned*)d_ws;                 // 1.6M uints fp8 x (6.4 MB)
    unsigned* fc      = xq + (size_t)N_NODES * 16;       // 391 -> pad 512
    int* offsets      = (int*)(fc + 512);                // N_NODES -> pad 100004
    unsigned* bpairs  = (unsigned*)(offsets + 100004);   // NBKT*REG + 64 (csr in place)

    hipMemsetAsync(fc, 0, 512 * sizeof(unsigned), stream);

    scatter_cvt<<<NBKT + CVT_BLKS, SCB, 0, stream>>>(x, xq, ei, fc, bpairs);
    bucket_csr<<<NBKT, SCB, 0, stream>>>(fc, bpairs, offsets);

    {
        const int waves  = (N_NODES + NPW - 1) / NPW;               // 6250
        const int blocks = (waves + (SBLK / 64) - 1) / (SBLK / 64); // 782
        sage_kernel<<<blocks, SBLK, 0, stream>>>(x, xq, offsets, (const int*)bpairs,
                                                 Wl, bl, Wr, out);
    }
}

// Round 17
// 84.766 us; speedup vs baseline: 1.4481x; 1.1872x over previous
//
#include <hip/hip_runtime.h>

#define N_NODES 100000
#define N_EDGES 1600000
#define D 64
#define NBKT 391                          // 256-node buckets: dst>>8
#define REG 5120                          // padded region stride (mean 4096 + 16 sigma)
#define A_EPB 4096                        // edges per scatter block
#define SCB 1024                          // scatter/csr block threads
#define A_I4 (A_EPB / 4)                  // 1024 int4 per block (1 per thread)
#define N_I4 (N_EDGES / 4)                // 400000
#define TB 5                              // edges/thread in pass B (TB*1024 = 5120 = REG)

typedef __attribute__((ext_vector_type(8))) short bf16x8;
typedef __attribute__((ext_vector_type(4))) float f32x4;

__device__ __forceinline__ unsigned short f2bf(float f) {
    union { float f; unsigned u; } v; v.f = f;
    unsigned r = v.u + 0x7FFFu + ((v.u >> 16) & 1u);
    return (unsigned short)(r >> 16);
}

// ---------------- kernel A: scatter into padded bucket regions + x->fp8 convert ----
#define CVT_ITEMS ((N_NODES * D) / 4)     // 1.6M items: 4 floats -> 1 packed fp8 uint
#define CVT_BLKS 1563                     // 1563 * 1024 = 1600512 >= 1.6M
__global__ __launch_bounds__(SCB) void scatter_cvt(const float* __restrict__ x,
                                                   unsigned* __restrict__ xq,
                                                   const int* __restrict__ ei,
                                                   unsigned* __restrict__ fc,
                                                   unsigned* __restrict__ bpairs) {
    __shared__ unsigned hc[NBKT];
    __shared__ unsigned hb[NBKT];
    const int blk = blockIdx.x;
    const int tid = threadIdx.x;
    if (blk < NBKT) {
        if (tid < NBKT) hc[tid] = 0;
        __syncthreads();

        const int g = blk * A_I4 + tid;            // one int4 (4 edges) per thread
        const int4* sptr = (const int4*)ei;
        const int4* dptr = (const int4*)(ei + N_EDGES);

        unsigned pay[4];     // (src<<8) | (dst & 255)
        unsigned meta[4];    // (bucket<<13) | lrank ; 0xFFFFFFFF = invalid
        if (g < N_I4) {
            int4 s4 = sptr[g];
            int4 d4 = dptr[g];
            const int dd[4] = { d4.x, d4.y, d4.z, d4.w };
            const int ss[4] = { s4.x, s4.y, s4.z, s4.w };
            #pragma unroll
            for (int c = 0; c < 4; ++c) {
                const unsigned b = (unsigned)dd[c] >> 8;
                const unsigned lr = atomicAdd(&hc[b], 1u);
                meta[c] = (b << 13) | lr;
                pay[c]  = ((unsigned)ss[c] << 8) | ((unsigned)dd[c] & 255u);
            }
        } else {
            #pragma unroll
            for (int c = 0; c < 4; ++c) meta[c] = 0xFFFFFFFFu;
        }
        __syncthreads();
        if (tid < NBKT) {
            unsigned c = hc[tid];
            if (c) hb[tid] = atomicAdd(&fc[tid], c);   // fixed bases: no pre-scan
        }
        __syncthreads();
        #pragma unroll
        for (int e = 0; e < 4; ++e) {
            if (meta[e] != 0xFFFFFFFFu) {
                const unsigned b   = meta[e] >> 13;
                const unsigned lr  = meta[e] & 0x1FFFu;
                const unsigned pos = hb[b] + lr;
                if (pos < REG) bpairs[(size_t)b * REG + pos] = pay[e];  // safety clamp
            }
        }
    } else {
        const int j = (blk - NBKT) * SCB + tid;    // packed-fp8 item
        if (j < CVT_ITEMS) {
            float4 v = ((const float4*)x)[j];
            unsigned u = __builtin_amdgcn_cvt_pk_fp8_f32(v.x, v.y, 0u, false);
            u = __builtin_amdgcn_cvt_pk_fp8_f32(v.z, v.w, u, true);
            xq[j] = u;
        }
    }
}

// ---------------- kernel B: per-bucket CSR build (in place) + packed offsets ----------------
// offsets[n] = (deg << 13) | rel_start   (rel within bucket region; abs = bucket*REG + rel)
__global__ __launch_bounds__(SCB) void bucket_csr(const unsigned* __restrict__ fc,
                                                  unsigned* __restrict__ bpairs,
                                                  int* __restrict__ offsets) {
    __shared__ unsigned ncnt[256];
    __shared__ unsigned s[256];
    const int b   = blockIdx.x;
    const int tid = threadIdx.x;
    const unsigned base = (unsigned)b * REG;
    unsigned cnt = fc[b];
    if (cnt > REG) cnt = REG;              // safety clamp

    if (tid < 256) ncnt[tid] = 0;
    __syncthreads();

    unsigned pk[TB];
    unsigned rk[TB];
    #pragma unroll
    for (int t = 0; t < TB; ++t) {
        const unsigned i = (unsigned)tid + t * (unsigned)SCB;
        if (i < cnt) {
            const unsigned p = bpairs[base + i];
            pk[t] = p;
            rk[t] = atomicAdd(&ncnt[p & 255u], 1u);
        } else {
            pk[t] = 0xFFFFFFFFu;
        }
    }
    __syncthreads();

    // 256-wide inclusive scan of ncnt on tids 0-255 (block-wide barriers)
    unsigned v = 0;
    if (tid < 256) { v = ncnt[tid]; s[tid] = v; }
    __syncthreads();
    for (int off = 1; off < 256; off <<= 1) {
        unsigned u = 0;
        if (tid < 256 && tid >= off) u = s[tid - off];
        __syncthreads();
        if (tid < 256) s[tid] += u;
        __syncthreads();
    }
    if (tid < 256) {
        const unsigned excl = s[tid] - v;
        ncnt[tid] = excl;                   // reuse as per-node local offset
        const int n0 = b * 256;
        if (n0 + tid < N_NODES) offsets[n0 + tid] = (int)((v << 13) | excl);
    }
    __syncthreads();

    #pragma unroll
    for (int t = 0; t < TB; ++t) {
        if (pk[t] != 0xFFFFFFFFu) {
            const unsigned p  = pk[t];
            const unsigned dl = p & 255u;
            bpairs[base + ncnt[dl] + rk[t]] = p >> 8;   // src
        }
    }
}

// fp8 gather step: 4 sub-iters x 4 edges. Lane group grp = lane>>4 takes edge
// e+grp via ONE ds_bpermute (replaces 4 readlane + 3 cndmask select tree);
// each lane holds 4 fp8 cols of that edge's row (1 line/row). si lanes >= deg
// hold a clamped valid index, so the bpermuted address is always safe.
#define STEPF(SI, J, N, A0, A1, A2, A3)                                      \
    {                                                                         \
        _Pragma("unroll")                                                     \
        for (int t_ = 0; t_ < 4; ++t_) {                                      \
            const int e_  = (J) + 4 * t_;                                     \
            const int sel_ = __shfl((SI), e_ + grp, 64);                      \
            unsigned v_ = xq32[(size_t)sel_ * 16 + lq];                       \
            v_ = (e_ + grp < (N)) ? v_ : 0u;                                  \
            (A0) += __builtin_amdgcn_cvt_f32_fp8(v_, 0);                      \
            (A1) += __builtin_amdgcn_cvt_f32_fp8(v_, 1);                      \
            (A2) += __builtin_amdgcn_cvt_f32_fp8(v_, 2);                      \
            (A3) += __builtin_amdgcn_cvt_f32_fp8(v_, 3);                      \
        }                                                                     \
    }

// rare tail for degree > 64
#define TAILF(S0, DD, A0, A1, A2, A3)                                        \
    for (int b2_ = 64; b2_ < (DD); b2_ += 64) {                              \
        const int n2_ = ((DD) - b2_ < 64) ? ((DD) - b2_) : 64;               \
        const int cl2_ = (lane < n2_) ? lane : (n2_ - 1);                    \
        const int sit_ = csr[(S0) + b2_ + cl2_];                             \
        for (int j_ = 0; j_ < n2_; j_ += 16) {                               \
            STEPF(sit_, j_, n2_, A0, A1, A2, A3)                             \
        }                                                                     \
    }

// finish one node: cross-group butterfly, mean, bf16-pack, LDS store (lanes 0-15)
#define FINR(R, DV, A0, A1, A2, A3)                                          \
    {                                                                         \
        (A0) += __shfl_xor((A0), 16, 64); (A0) += __shfl_xor((A0), 32, 64);   \
        (A1) += __shfl_xor((A1), 16, 64); (A1) += __shfl_xor((A1), 32, 64);   \
        (A2) += __shfl_xor((A2), 16, 64); (A2) += __shfl_xor((A2), 32, 64);   \
        (A3) += __shfl_xor((A3), 16, 64); (A3) += __shfl_xor((A3), 32, 64);   \
        const float inv_ = 1.0f / fmaxf((float)(DV), 1.0f);                   \
        if (lane < 16) {                                                      \
            const unsigned m0_ = ((unsigned)f2bf((A1) * inv_) << 16)          \
                                 | f2bf((A0) * inv_);                         \
            const unsigned m1_ = ((unsigned)f2bf((A3) * inv_) << 16)          \
                                 | f2bf((A2) * inv_);                         \
            const int sw_ = ((R) & 7) << 2;                                   \
            sAw[((R) * 64 + 2 * lane) ^ sw_]     = m0_;                       \
            sAw[((R) * 64 + 2 * lane + 1) ^ sw_] = m1_;                       \
        }                                                                     \
    }

// ---------------- fused gather(fp8) + mean + MFMA matmul + bias + ReLU ----------------
#define NPW 16
#define SBLK 512
__global__ __launch_bounds__(SBLK) void sage_kernel(const float* __restrict__ x,
                                                    const unsigned* __restrict__ xq32,
                                                    const int* __restrict__ offsets,
                                                    const int* __restrict__ csr,
                                                    const float* __restrict__ Wl,
                                                    const float* __restrict__ bl,
                                                    const float* __restrict__ Wr,
                                                    float* __restrict__ out) {
    __shared__ unsigned short sWt[D * 2 * D];      // 64 cols x 128 k, 16 KB
    __shared__ float sbl[D];
    __shared__ unsigned int sA32[(SBLK / 64) * NPW * (2 * D / 2)];  // 8 waves x 16 rows x 64 uints

    const int tid = threadIdx.x;
    for (int i = tid; i < D * D; i += SBLK) {
        int k = i >> 6, c = i & 63;
        int swz = (c & 7) << 3;                     // ushort-index xor
        sWt[(c * 128 + k) ^ swz]      = f2bf(Wl[i]);
        sWt[(c * 128 + 64 + k) ^ swz] = f2bf(Wr[i]);
    }
    if (tid < D) sbl[tid] = bl[tid];
    __syncthreads();

    const int lane = tid & 63;
    const int wib  = tid >> 6;
    const int wid  = (blockIdx.x * (SBLK / 64)) + wib;
    const int node0 = wid * NPW;
    if (node0 >= N_NODES) return;

    unsigned int* sAw = sA32 + wib * (NPW * 64);
    const int grp = lane >> 4;                      // 0..3 edge-group
    const int lq  = lane & 15;                      // col-quad within row
    const int bb = (node0 >> 8) * REG;              // bucket base (wave's nodes share it)

    // ---- stage self rows from f32 x (contiguous; 8 insts, 2 rows each) ----
    {
        const float2* __restrict__ x2 = (const float2*)x;
        const int c = lane & 31;
        #pragma unroll
        for (int rr = 0; rr < 8; ++rr) {
            const int r = 2 * rr + (lane >> 5);
            float2 v = x2[(size_t)(node0 + r) * 32 + c];
            const unsigned mp = ((unsigned)f2bf(v.y) << 16) | f2bf(v.x);
            sAw[(r * 64 + 32 + c) ^ ((r & 7) << 2)] = mp;
        }
    }

    // ---- stage packed offsets for 16 nodes with one lane-parallel load ----
    const int offl = offsets[node0 + (lane & 15)];

    // ---- stage csr chunk 0 for all 16 nodes (16 loads in flight) ----
    int si[NPW];
    int dg[NPW];
    #pragma unroll
    for (int r = 0; r < NPW; ++r) {
        const int er = __builtin_amdgcn_readlane(offl, r);
        const int d  = (int)((unsigned)er >> 13);
        dg[r] = d;
        const int s0 = bb + (er & 0x1FFF);
        const int dm = (d > 0) ? d : 1;
        const int cl = (lane < dm) ? lane : (dm - 1);
        si[r] = csr[s0 + cl];
    }

    // ---- gather: two nodes interleaved, fp8 rows (1 line/edge) ----
    #pragma unroll
    for (int p = 0; p < NPW / 2; ++p) {
        const int rA = 2 * p, rB = 2 * p + 1;
        const int dA = dg[rA], dB = dg[rB];
        const int nA = (dA < 64) ? dA : 64;
        const int nB = (dB < 64) ? dB : 64;

        float a0 = 0.0f, a1 = 0.0f, a2 = 0.0f, a3 = 0.0f;
        float b0 = 0.0f, b1 = 0.0f, b2 = 0.0f, b3 = 0.0f;
        int jA = 0, jB = 0;
        while (jA < nA && jB < nB) {
            STEPF(si[rA], jA, nA, a0, a1, a2, a3)
            STEPF(si[rB], jB, nB, b0, b1, b2, b3)
            jA += 16; jB += 16;
        }
        while (jA < nA) { STEPF(si[rA], jA, nA, a0, a1, a2, a3) jA += 16; }
        while (jB < nB) { STEPF(si[rB], jB, nB, b0, b1, b2, b3) jB += 16; }
        if (dA > 64) {
            const int s0A = bb + (__builtin_amdgcn_readlane(offl, rA) & 0x1FFF);
            TAILF(s0A, dA, a0, a1, a2, a3)
        }
        if (dB > 64) {
            const int s0B = bb + (__builtin_amdgcn_readlane(offl, rB) & 0x1FFF);
            TAILF(s0B, dB, b0, b1, b2, b3)
        }

        FINR(rA, dA, a0, a1, a2, a3)
        FINR(rB, dB, b0, b1, b2, b3)
    }

    // ---- MFMA phase ----
    const unsigned short* sAu = (const unsigned short*)sAw;
    const int row = lane & 15;
    const int kb  = lane >> 4;

    bf16x8 afr[4];
    #pragma unroll
    for (int kc = 0; kc < 4; ++kc) {
        int us = (row * 128 + kc * 32 + kb * 8) ^ ((row & 7) << 3);
        afr[kc] = *(const bf16x8*)(sAu + us);
    }

    #pragma unroll
    for (int ct = 0; ct < 4; ++ct) {
        const int col = ct * 16 + row;
        f32x4 acc = {0.0f, 0.0f, 0.0f, 0.0f};
        #pragma unroll
        for (int kc = 0; kc < 4; ++kc) {
            int us = (col * 128 + kc * 32 + kb * 8) ^ ((col & 7) << 3);
            bf16x8 bfr = *(const bf16x8*)(sWt + us);
            acc = __builtin_amdgcn_mfma_f32_16x16x32_bf16(afr[kc], bfr, acc, 0, 0, 0);
        }
        const float bias = sbl[col];
        const int crow0 = (lane >> 4) * 4;
        #pragma unroll
        for (int i = 0; i < 4; ++i) {
            out[(node0 + crow0 + i) * D + col] = fmaxf(acc[i] + bias, 0.0f);
        }
    }
}

// ---------------- launch ----------------
extern "C" void kernel_launch(void* const* d_in, const int* in_sizes, int n_in,
                              void* d_out, int out_size, void* d_ws, size_t ws_size,
                              hipStream_t stream) {
    const float* x  = (const float*)d_in[0];
    const int*   ei = (const int*)d_in[1];    // [2, N_EDGES] flat: src then dst
    const float* Wl = (const float*)d_in[2];
    const float* bl = (const float*)d_in[3];
    const float* Wr = (const float*)d_in[4];
    float* out = (float*)d_out;

    // workspace layout (~14.8 MB), 16B-aligned segments
    unsigned* xq      = (unsigned*)d_ws;                 // 1.6M uints fp8 x (6.4 MB)
    unsigned* fc      = xq + (size_t)N_NODES * 16;       // 391 -> pad 512
    int* offsets      = (int*)(fc + 512);                // N_NODES -> pad 100004
    unsigned* bpairs  = (unsigned*)(offsets + 100004);   // NBKT*REG + 64 (csr in place)

    hipMemsetAsync(fc, 0, 512 * sizeof(unsigned), stream);

    scatter_cvt<<<NBKT + CVT_BLKS, SCB, 0, stream>>>(x, xq, ei, fc, bpairs);
    bucket_csr<<<NBKT, SCB, 0, stream>>>(fc, bpairs, offsets);

    {
        const int waves  = (N_NODES + NPW - 1) / NPW;               // 6250
        const int blocks = (waves + (SBLK / 64) - 1) / (SBLK / 64); // 782
        sage_kernel<<<blocks, SBLK, 0, stream>>>(x, xq, offsets, (const int*)bpairs,
                                                 Wl, bl, Wr, out);
    }
}